// Round 7
// baseline (289.629 us; speedup 1.0000x reference)
//
#include <hip/hip_runtime.h>
#include <hip/hip_bf16.h>

#define TPB 256
#define CPB 256

using f32x4  = __attribute__((ext_vector_type(4))) float;
using bf16x8 = __attribute__((ext_vector_type(8))) short;

// Problem constants (B=4096, L=32, E=512, D=64)
static constexpr int BB = 4096;
static constexpr size_t NTOT = (size_t)BB * BB; // 16777216

// Workspace layout (bytes)
static constexpr size_t OFF_AHI  = 0;                        // a_hi [B][512] bf16 = 4 MB
static constexpr size_t OFF_D1   = 8388608;                  // d1 [B] f32 = 16 KB
static constexpr size_t OFF_H1   = OFF_D1 + 16384;           // hist1 u32[2048]
static constexpr size_t OFF_H2   = OFF_H1 + 8192;            // hist2 u32[2048]
static constexpr size_t OFF_H3   = OFF_H2 + 8192;            // hist3 u32[1024]
static constexpr size_t OFF_GS3  = OFF_H3 + 4096;            // gsum3 double[1024]
static constexpr size_t OFF_ST   = OFF_GS3 + 8192;           // state u32[8] + double[3]
static constexpr size_t OFF_HS   = OFF_ST + 256;             // h1hi,h1lo,h2hi,h2lo bf16 [B][64]
static constexpr size_t HS_ONE   = (size_t)BB * 64 * 2;      // 512 KB
static constexpr size_t OFF_COST = OFF_HS + 4 * HS_ONE;      // cost f32 [B*B] = 64 MB
static constexpr size_t NEED_MAT = OFF_COST + NTOT * 4;
static constexpr size_t ZERO_OFF = OFF_H1;
static constexpr size_t ZERO_LEN = (OFF_ST + 256) - OFF_H1;  // 28928 B

// ---------------- helpers ----------------
__device__ __forceinline__ void bsplit(float x, unsigned short& h, unsigned short& l)
{
    unsigned b = __float_as_uint(x);
    unsigned r = (b + 0x7FFFu + ((b >> 16) & 1u)) >> 16;       // rne bf16
    h = (unsigned short)r;
    float hf = __uint_as_float(r << 16);
    float lof = x - hf;                                        // exact in f32
    unsigned b2 = __float_as_uint(lof);
    unsigned r2 = (b2 + 0x7FFFu + ((b2 >> 16) & 1u)) >> 16;
    l = (unsigned short)r2;
}

__device__ __forceinline__ unsigned short b2h(float x)
{
    unsigned b = __float_as_uint(x);
    return (unsigned short)((b + 0x7FFFu + ((b >> 16) & 1u)) >> 16);
}

__device__ __forceinline__ void gload16(const void* g, void* l)
{
    __builtin_amdgcn_global_load_lds((const __attribute__((address_space(1))) void*)g,
                                     (__attribute__((address_space(3))) void*)l,
                                     16, 0, 0);
}

// ---------------- zero the hist/state region ----------------
__global__ __launch_bounds__(TPB) void zero_k(char* base)
{
    unsigned* z = (unsigned*)(base + ZERO_OFF);
    const int n = (int)(ZERO_LEN / 4);
    for (int i = blockIdx.x * TPB + threadIdx.x; i < n; i += gridDim.x * TPB) z[i] = 0u;
}

// ---------------- prep: softmax(sim) -> caps_mean -> normalized a (bf16) ----------------
__global__ __launch_bounds__(TPB) void prep_kernel(const float* __restrict__ caps,
                                                   const float* __restrict__ sim,
                                                   unsigned short* __restrict__ ahi)
{
    const int b = blockIdx.x;
    const int tid = threadIdx.x;
    __shared__ float sm[32];
    __shared__ float w[32];
    __shared__ float red[4];
    __shared__ float nrm;
    if (tid < 32) sm[tid] = sim[b * 32 + tid];
    __syncthreads();
    if (tid < 32) {
        float m = -1e30f;
        for (int l = 0; l < 32; ++l) m = fmaxf(m, sm[l]);
        float ssum = 0.f;
        for (int l = 0; l < 32; ++l) ssum += expf(sm[l] - m);
        w[tid] = expf(sm[tid] - m) / ssum;
    }
    __syncthreads();
    const float2* cb2 = (const float2*)(caps + (size_t)b * 32 * 512);
    float cx = 0.f, cy = 0.f;
    for (int l = 0; l < 32; ++l) {
        float wl = w[l];
        float2 v = cb2[l * 256 + tid];
        cx = fmaf(wl, v.x, cx);
        cy = fmaf(wl, v.y, cy);
    }
    float ss = cx * cx + cy * cy;
    #pragma unroll
    for (int off = 32; off; off >>= 1) ss += __shfl_down(ss, off, 64);
    if ((tid & 63) == 0) red[tid >> 6] = ss;
    __syncthreads();
    if (tid == 0) nrm = sqrtf(red[0] + red[1] + red[2] + red[3]);
    __syncthreads();
    float an = fmaxf(nrm, 1e-5f);
    ahi[(size_t)b * 512 + 2 * tid]     = b2h(cx / an);
    ahi[(size_t)b * 512 + 2 * tid + 1] = b2h(cy / an);
}

// ---------------- fused: splith + diag + loss2 + loss3 (4 rows / block) ----------------
__global__ __launch_bounds__(TPB) void small_k(const float* __restrict__ h1f,
                                               const float* __restrict__ h2f,
                                               unsigned short* __restrict__ h1hi,
                                               unsigned short* __restrict__ h1lo,
                                               unsigned short* __restrict__ h2hi,
                                               unsigned short* __restrict__ h2lo,
                                               float* __restrict__ d1,
                                               const float* __restrict__ sv,
                                               const float* __restrict__ sv2,
                                               double* __restrict__ L)
{
    const int row  = (blockIdx.x << 2) + (threadIdx.x >> 6);
    const int lane = threadIdx.x & 63;
    const int i    = (row << 6) + lane;
    float x1 = h1f[i], x2 = h2f[i];
    unsigned short h, l;
    bsplit(x1, h, l); h1hi[i] = h; h1lo[i] = l;
    bsplit(x2, h, l); h2hi[i] = h; h2lo[i] = l;
    // diag
    float p = x1 * x2;
    #pragma unroll
    for (int m = 32; m; m >>= 1) p += __shfl_xor(p, m, 64);
    if (lane == 0) d1[row] = p;
    // loss2 partial (raw sum of (h1-0.5)^2)
    float xq = x1 - 0.5f;
    double s2 = (double)(xq * xq);
    #pragma unroll
    for (int m = 32; m; m >>= 1) s2 += __shfl_xor(s2, m, 64);
    // loss3 row term
    float xt = sv[i] / 0.1f;
    float xs = sv2[i] / 0.1f;
    float mt = xt, ms = xs;
    #pragma unroll
    for (int m = 32; m; m >>= 1) {
        mt = fmaxf(mt, __shfl_xor(mt, m, 64));
        ms = fmaxf(ms, __shfl_xor(ms, m, 64));
    }
    float et = expf(xt - mt), es = expf(xs - ms);
    float sst = et, sss = es;
    #pragma unroll
    for (int m = 32; m; m >>= 1) { sst += __shfl_xor(sst, m, 64); sss += __shfl_xor(sss, m, 64); }
    float pt = (xt - mt) - logf(sst);
    float ps = (xs - ms) - logf(sss);
    double d3 = (double)((et / sst) * (pt - ps));
    #pragma unroll
    for (int m = 32; m; m >>= 1) d3 += __shfl_xor(d3, m, 64);
    __shared__ double r2[4], r3[4];
    if (lane == 0) { r2[threadIdx.x >> 6] = s2; r3[threadIdx.x >> 6] = d3; }
    __syncthreads();
    if (threadIdx.x == 0) {
        atomicAdd(L + 1, r2[0] + r2[1] + r2[2] + r2[3]);
        atomicAdd(L + 2, r3[0] + r3[1] + r3[2] + r3[3]);
    }
}

// ---------------- per-value selection logic ----------------
template<int MODE>
__device__ __forceinline__ void process_val(float v, unsigned b1, unsigned b2,
    unsigned* lh, double* gsum3, double& dsum, unsigned& nclamp, unsigned CB)
{
    unsigned bits = __float_as_uint(v);
    if (MODE == 0) {
        if (bits == CB) ++nclamp;
        else atomicAdd(&lh[bits >> 21], 1u);
    } else if (MODE == 1) {
        unsigned p = bits >> 21;
        if (p < b1) dsum += (double)v;
        else if (p == b1) {
            if (bits == CB) ++nclamp;
            else atomicAdd(&lh[(bits >> 10) & 2047u], 1u);
        }
    } else {
        unsigned q2 = bits >> 10;
        if ((q2 >> 11) == b1) {
            unsigned m = q2 & 2047u;
            if (m < b2) dsum += (double)v;
            else if (m == b2) {
                if (bits == CB) ++nclamp;
                else {
                    atomicAdd(&lh[bits & 1023u], 1u);
                    atomicAdd(&gsum3[bits & 1023u], (double)v);
                }
            }
        }
    }
}

template<int MODE, int NW>
__device__ __forceinline__ void flush_pass(unsigned* lh, unsigned* hist,
    double* gsum3, double dsum, unsigned nclamp, double* lossAcc,
    double* red, unsigned CB)
{
    if (nclamp) {
        if (MODE == 0) atomicAdd(&lh[CB >> 21], nclamp);
        else if (MODE == 1) atomicAdd(&lh[(CB >> 10) & 2047u], nclamp);
        else {
            atomicAdd(&lh[CB & 1023u], nclamp);
            atomicAdd(&gsum3[CB & 1023u], (double)nclamp * (double)(1e-8f));
        }
    }
    __syncthreads();
    constexpr int NB = (MODE == 2) ? 1024 : 2048;
    for (int q = threadIdx.x; q < NB; q += NW * 64) {
        unsigned c = lh[q];
        if (c) atomicAdd(&hist[q], c);
    }
    if (MODE >= 1) {
        #pragma unroll
        for (int off = 32; off; off >>= 1) dsum += __shfl_down(dsum, off, 64);
        if ((threadIdx.x & 63) == 0) red[threadIdx.x >> 6] = dsum;
        __syncthreads();
        if (threadIdx.x == 0) {
            double t = 0.0;
            #pragma unroll
            for (int wv = 0; wv < NW; ++wv) t += red[wv];
            atomicAdd(lossAcc, t);
        }
    }
}

// ---------------- fused MFMA cost GEMM + selection pass ----------------
// 128x128 tile / block, 256 threads = 4 waves (2x2), wave tile 64x64 (4x4 frags,
// 128 acc VGPR). cos: plain bf16 K=512 in 8 rounds of K=64; scores: 3-product
// split bf16 K=64 in 2 rounds of K=32. TWO LDS buffers (72KB total -> 2 blocks/CU,
// 4 waves/SIMD), dist-1 COUNTED vmcnt(8) (no drain), two barriers/round
// (barrier2 protects buffer reuse). Involution XOR slot swizzle. 8x16 XCD chunk.
template<int MODE, bool STORE>
__global__ __launch_bounds__(CPB, 2) void cost_pass(
    const unsigned short* __restrict__ ahi,
    const unsigned short* __restrict__ h1hi, const unsigned short* __restrict__ h1lo,
    const unsigned short* __restrict__ h2hi, const unsigned short* __restrict__ h2lo,
    const float* __restrict__ d1, float* __restrict__ cost,
    const unsigned* __restrict__ st, unsigned* __restrict__ hist,
    double* __restrict__ gsum3, double* __restrict__ lossAcc)
{
    constexpr int NB = (MODE == 2) ? 1024 : 2048;
    __shared__ char lds_raw[65536];   // 2 bufs x 32KB
    __shared__ float sD1[128];
    __shared__ unsigned lh[NB];
    __shared__ double red[4];
    const int tid  = threadIdx.x;
    const int lane = tid & 63;
    const int wid  = tid >> 6;        // 0..3
    const int wr   = wid >> 1;        // 0..1 : 64-row band
    const int wc   = wid & 1;         // 0..1 : 64-col band

    // per-XCD 8x16 chunk (1024 blocks; HW round-robins blockIdx%8 across XCDs)
    const int orig = (int)blockIdx.x;
    const int xcd  = orig & 7;
    const int idx  = orig >> 3;             // 0..127
    const int bi   = (((xcd >> 1) << 3) + (idx & 7)) << 7;
    const int bj   = (((xcd & 1) << 4) + (idx >> 3)) << 7;

    f32x4 accC[4][4], accS[4][4];
    #pragma unroll
    for (int m = 0; m < 4; ++m)
        #pragma unroll
        for (int n = 0; n < 4; ++n)
            #pragma unroll
            for (int q = 0; q < 4; ++q) { accC[m][n][q] = 0.f; accS[m][n][q] = 0.f; }

    auto STAGE = [&](int t) {
        char* d = lds_raw + ((size_t)(t & 1) << 15);
        if (t < 8) {
            const int k0b = t << 7;                  // 64 bf16 = 128B per round
            #pragma unroll
            for (int q = 0; q < 4; ++q) {
                int o    = (q << 12) + (tid << 4);   // 0..16383
                int row  = o >> 7;
                int slot = (o >> 4) & 7;
                int sc   = (slot ^ (row & 7)) << 4;  // inverse swizzle on global src
                gload16((const char*)ahi + (size_t)(bi + row) * 1024 + k0b + sc, d + o);
                gload16((const char*)ahi + (size_t)(bj + row) * 1024 + k0b + sc, d + 16384 + o);
            }
        } else {
            const int k0b = (t - 8) << 6;            // 32 bf16 = 64B per round
            #pragma unroll
            for (int q = 0; q < 2; ++q) {
                int o    = (q << 12) + (tid << 4);   // 0..8191
                int row  = o >> 6;
                int slot = (o >> 4) & 3;
                int sc   = (slot ^ ((row >> 1) & 3)) << 4;
                size_t ra = (size_t)(bi + row) * 128 + k0b + sc;
                size_t rb = (size_t)(bj + row) * 128 + k0b + sc;
                gload16((const char*)h1hi + ra, d + o);
                gload16((const char*)h1lo + ra, d + 8192 + o);
                gload16((const char*)h2hi + rb, d + 16384 + o);
                gload16((const char*)h2lo + rb, d + 24576 + o);
            }
        }
    };

    STAGE(0);
    #pragma unroll 1
    for (int t = 0; t < 10; ++t) {
        if (t < 9) STAGE(t + 1);
        __builtin_amdgcn_sched_barrier(0);
        if (t < 9) asm volatile("s_waitcnt vmcnt(8)" ::: "memory");
        else       asm volatile("s_waitcnt vmcnt(0)" ::: "memory");
        __builtin_amdgcn_s_barrier();          // round t data visible to all waves
        const char* bufb = lds_raw + ((size_t)(t & 1) << 15);
        if (t < 8) {
            // cos: [128][128B] tiles, slot swizzle p ^ (row&7)
            #pragma unroll
            for (int ks = 0; ks < 2; ++ks) {
                bf16x8 a_[4], b_[4];
                const int pbase = (ks << 2) + (lane >> 4);
                #pragma unroll
                for (int m = 0; m < 4; ++m) {
                    int row = wr * 64 + m * 16 + (lane & 15);
                    a_[m] = *(const bf16x8*)(bufb + row * 128 + ((pbase ^ (row & 7)) << 4));
                }
                #pragma unroll
                for (int n = 0; n < 4; ++n) {
                    int row = wc * 64 + n * 16 + (lane & 15);
                    b_[n] = *(const bf16x8*)(bufb + 16384 + row * 128 + ((pbase ^ (row & 7)) << 4));
                }
                __builtin_amdgcn_s_setprio(1);
                #pragma unroll
                for (int m = 0; m < 4; ++m)
                    #pragma unroll
                    for (int n = 0; n < 4; ++n)
                        accC[m][n] = __builtin_amdgcn_mfma_f32_16x16x32_bf16(a_[m], b_[n], accC[m][n], 0, 0, 0);
                __builtin_amdgcn_s_setprio(0);
            }
        } else {
            // scores: [128][64B] tiles
            const int rdsw0 = (lane >> 4);
            bf16x8 ah[4], bh[4], bl[4];
            #pragma unroll
            for (int m = 0; m < 4; ++m) {
                int row = wr * 64 + m * 16 + (lane & 15);
                ah[m] = *(const bf16x8*)(bufb + row * 64 + ((rdsw0 ^ ((row >> 1) & 3)) << 4));
            }
            #pragma unroll
            for (int n = 0; n < 4; ++n) {
                int row = wc * 64 + n * 16 + (lane & 15);
                int sw  = ((rdsw0 ^ ((row >> 1) & 3)) << 4);
                bh[n] = *(const bf16x8*)(bufb + 16384 + row * 64 + sw);
                bl[n] = *(const bf16x8*)(bufb + 24576 + row * 64 + sw);
            }
            __builtin_amdgcn_s_setprio(1);
            #pragma unroll
            for (int m = 0; m < 4; ++m)
                #pragma unroll
                for (int n = 0; n < 4; ++n) {
                    accS[m][n] = __builtin_amdgcn_mfma_f32_16x16x32_bf16(ah[m], bh[n], accS[m][n], 0, 0, 0);
                    accS[m][n] = __builtin_amdgcn_mfma_f32_16x16x32_bf16(ah[m], bl[n], accS[m][n], 0, 0, 0);
                }
            __builtin_amdgcn_s_setprio(0);
            bf16x8 al[4];
            #pragma unroll
            for (int m = 0; m < 4; ++m) {
                int row = wr * 64 + m * 16 + (lane & 15);
                al[m] = *(const bf16x8*)(bufb + 8192 + row * 64 + ((rdsw0 ^ ((row >> 1) & 3)) << 4));
            }
            __builtin_amdgcn_s_setprio(1);
            #pragma unroll
            for (int m = 0; m < 4; ++m)
                #pragma unroll
                for (int n = 0; n < 4; ++n)
                    accS[m][n] = __builtin_amdgcn_mfma_f32_16x16x32_bf16(al[m], bh[n], accS[m][n], 0, 0, 0);
            __builtin_amdgcn_s_setprio(0);
        }
        __builtin_amdgcn_sched_barrier(0);
        __builtin_amdgcn_s_barrier();          // all reads of buf(t) done before reuse
    }

    // epilogue: cost values -> store + selection
    if (tid < 128) sD1[tid] = d1[bi + tid];
    for (int q = tid; q < NB; q += CPB) lh[q] = 0u;
    __syncthreads();
    const unsigned CB = __float_as_uint(1e-8f);
    unsigned b1 = 0, b2 = 0;
    if (MODE >= 1) b1 = st[0];
    if (MODE == 2) b2 = st[2];
    unsigned nclamp = 0;
    double dsum = 0.0;
    #pragma unroll
    for (int m = 0; m < 4; ++m) {
        #pragma unroll
        for (int r = 0; r < 4; ++r) {
            const int irow = wr * 64 + m * 16 + (lane >> 4) * 4 + r;
            const int i = bi + irow;
            const float di = sD1[irow];
            #pragma unroll
            for (int n = 0; n < 4; ++n) {
                const int j = bj + wc * 64 + n * 16 + (lane & 15);
                float cosv = fminf(fmaxf(accC[m][n][r], 1e-6f), 0.999999f);
                float v = (1.0f - cosv) * 0.2f + accS[m][n][r] - di;
                v = fmaxf(v, 1e-8f);
                if (i == j) v = 0.0f;
                if constexpr (STORE) cost[(size_t)i * 4096 + j] = v;
                process_val<MODE>(v, b1, b2, lh, gsum3, dsum, nclamp, CB);
            }
        }
    }
    flush_pass<MODE, 4>(lh, hist, gsum3, dsum, nclamp, lossAcc, red, CB);
}

// ---------------- elementwise passes over materialized cost ----------------
template<int MODE>
__global__ __launch_bounds__(TPB) void pass_mat(
    const float4* __restrict__ cost4, const unsigned* __restrict__ st,
    unsigned* __restrict__ hist, double* __restrict__ gsum3,
    double* __restrict__ lossAcc)
{
    constexpr int NB = (MODE == 2) ? 1024 : 2048;
    __shared__ unsigned lh[NB];
    __shared__ double red[4];
    for (int q = threadIdx.x; q < NB; q += TPB) lh[q] = 0u;
    __syncthreads();
    const unsigned CB = __float_as_uint(1e-8f);
    unsigned b1 = st[0];
    unsigned b2 = (MODE == 2) ? st[2] : 0u;
    unsigned nclamp = 0;
    double dsum = 0.0;
    const int stride = gridDim.x * TPB;
    for (int i = blockIdx.x * TPB + threadIdx.x; i < (int)(NTOT / 4); i += stride) {
        float4 v4 = cost4[i];
        process_val<MODE>(v4.x, b1, b2, lh, gsum3, dsum, nclamp, CB);
        process_val<MODE>(v4.y, b1, b2, lh, gsum3, dsum, nclamp, CB);
        process_val<MODE>(v4.z, b1, b2, lh, gsum3, dsum, nclamp, CB);
        process_val<MODE>(v4.w, b1, b2, lh, gsum3, dsum, nclamp, CB);
    }
    flush_pass<MODE, 4>(lh, hist, gsum3, dsum, nclamp, lossAcc, red, CB);
}

// ---------------- scan: find k-th within histogram; phase 3 also finalizes ----------------
__global__ __launch_bounds__(TPB) void scan_kernel(
    const unsigned* __restrict__ hist, int nbins, int phase,
    unsigned* __restrict__ st, const int* __restrict__ epochs_ptr,
    const double* __restrict__ gsum3, const double* __restrict__ lossAcc,
    const double* __restrict__ l2acc, const double* __restrict__ l3acc,
    float* __restrict__ out)
{
    const int tid = threadIdx.x;
    const int per = nbins >> 8;
    __shared__ unsigned wtot[4];
    __shared__ int sbin;
    __shared__ double dred[4];
    if (tid == 0) sbin = 0;

    unsigned k;
    if (phase == 1) {
        int ep = epochs_ptr[0];
        if (ep > 1000000 || ep < 0) ep = (int)__int_as_float(ep);
        double cr = (double)ep * 0.1;
        if (!(cr < 1.0)) cr = 0.99;
        double kd = ceil(16777216.0 * (1.0 - cr));
        if (kd < 1.0) kd = 1.0;
        if (kd > 16777216.0) kd = 16777216.0;
        k = (unsigned)kd;
    } else if (phase == 2) k = st[1];
    else k = st[3];

    unsigned local[8];
    unsigned s = 0;
    #pragma unroll
    for (int r = 0; r < 8; ++r) {
        unsigned v = (r < per) ? hist[tid * per + r] : 0u;
        local[r] = v; s += v;
    }
    unsigned inc = s;
    #pragma unroll
    for (int d = 1; d < 64; d <<= 1) {
        unsigned n = __shfl_up(inc, (unsigned)d, 64);
        if ((tid & 63) >= d) inc += n;
    }
    if ((tid & 63) == 63) wtot[tid >> 6] = inc;
    __syncthreads();
    unsigned woff = 0;
    for (int wv = 0; wv < (tid >> 6); ++wv) woff += wtot[wv];
    unsigned excl = woff + (inc - s);
    if (k > excl && k <= excl + s) {
        unsigned rem = k - excl;
        int bin = tid * per;
        for (int r = 0; r < per; ++r) {
            if (rem <= local[r]) { bin = tid * per + r; break; }
            rem -= local[r];
        }
        if (phase == 1) { st[0] = (unsigned)bin; st[1] = rem; }
        else if (phase == 2) { st[2] = (unsigned)bin; st[3] = rem; }
        else { st[4] = (unsigned)bin; sbin = bin; }
    }
    if (phase == 3) {
        __syncthreads();
        int b3 = sbin;
        double s3 = 0.0;
        for (int q = tid; q < 1024; q += TPB) if (q < b3) s3 += gsum3[q];
        #pragma unroll
        for (int off = 32; off; off >>= 1) s3 += __shfl_down(s3, off, 64);
        if ((tid & 63) == 0) dred[tid >> 6] = s3;
        __syncthreads();
        if (tid == 0) {
            double loss1 = lossAcc[0] + dred[0] + dred[1] + dred[2] + dred[3];
            double loss2 = -(l2acc[0]) / (64.0 * 4096.0);
            double loss3 = l3acc[0];
            double total = 0.5 * loss1 + 0.5 * loss2 + 0.5 * loss3
                         + 3.0 * 0.69314718055994530942;
            float v = (float)total;
            unsigned bits = __float_as_uint(v);
            unsigned lsb = (bits >> 16) & 1u;
            unsigned h = (bits + 0x7FFFu + lsb) >> 16;
            ((unsigned*)out)[0] = (bits & 0xFFFF0000u) | (h & 0xFFFFu);
        }
    }
}

extern "C" void kernel_launch(void* const* d_in, const int* in_sizes, int n_in,
                              void* d_out, int out_size, void* d_ws, size_t ws_size,
                              hipStream_t stream) {
    const float* h1f  = (const float*)d_in[0];
    const float* h2f  = (const float*)d_in[1];
    const float* caps = (const float*)d_in[2];
    const float* sim  = (const float*)d_in[3];
    const float* sv   = (const float*)d_in[4];
    const float* sv2  = (const float*)d_in[5];
    const int*   ep   = (const int*)d_in[6];

    char* base = (char*)d_ws;
    unsigned short* AHI  = (unsigned short*)(base + OFF_AHI);
    float*    D1   = (float*)(base + OFF_D1);
    unsigned* H1   = (unsigned*)(base + OFF_H1);
    unsigned* H2   = (unsigned*)(base + OFF_H2);
    unsigned* H3   = (unsigned*)(base + OFF_H3);
    double*   GS3  = (double*)(base + OFF_GS3);
    unsigned* ST   = (unsigned*)(base + OFF_ST);
    double*   L    = (double*)(base + OFF_ST + 32);
    unsigned short* H1HI = (unsigned short*)(base + OFF_HS);
    unsigned short* H1LO = (unsigned short*)(base + OFF_HS + HS_ONE);
    unsigned short* H2HI = (unsigned short*)(base + OFF_HS + 2 * HS_ONE);
    unsigned short* H2LO = (unsigned short*)(base + OFF_HS + 3 * HS_ONE);
    float*    COST = (float*)(base + OFF_COST);
    const bool mat = ws_size >= NEED_MAT;

    zero_k<<<8, TPB, 0, stream>>>(base);
    prep_kernel<<<4096, TPB, 0, stream>>>(caps, sim, AHI);
    small_k<<<1024, TPB, 0, stream>>>(h1f, h2f, H1HI, H1LO, H2HI, H2LO, D1, sv, sv2, L);

    if (mat)
        cost_pass<0, true ><<<1024, CPB, 0, stream>>>(AHI, H1HI, H1LO, H2HI, H2LO, D1, COST, ST, H1, GS3, L);
    else
        cost_pass<0, false><<<1024, CPB, 0, stream>>>(AHI, H1HI, H1LO, H2HI, H2LO, D1, nullptr, ST, H1, GS3, L);
    scan_kernel<<<1, TPB, 0, stream>>>(H1, 2048, 1, ST, ep, GS3, L, L + 1, L + 2, (float*)d_out);

    if (mat)
        pass_mat<1><<<4096, TPB, 0, stream>>>((const float4*)COST, ST, H2, GS3, L);
    else
        cost_pass<1, false><<<1024, CPB, 0, stream>>>(AHI, H1HI, H1LO, H2HI, H2LO, D1, nullptr, ST, H2, GS3, L);
    scan_kernel<<<1, TPB, 0, stream>>>(H2, 2048, 2, ST, ep, GS3, L, L + 1, L + 2, (float*)d_out);

    if (mat)
        pass_mat<2><<<4096, TPB, 0, stream>>>((const float4*)COST, ST, H3, GS3, L);
    else
        cost_pass<2, false><<<1024, CPB, 0, stream>>>(AHI, H1HI, H1LO, H2HI, H2LO, D1, nullptr, ST, H3, GS3, L);
    scan_kernel<<<1, TPB, 0, stream>>>(H3, 1024, 3, ST, ep, GS3, L, L + 1, L + 2, (float*)d_out);
}